// Round 5
// baseline (81.300 us; speedup 1.0000x reference)
//
#include <hip/hip_runtime.h>
#include <stdint.h>

#define N_TOK 4096
#define D_IN  64
#define NF    32
#define NH    4
#define OUTW  (NH * NF)        // 128
#define BT    16
#define NT    8

typedef float        f32x4  __attribute__((ext_vector_type(4)));
typedef unsigned int uint4v __attribute__((ext_vector_type(4)));
typedef __bf16       bf16x8 __attribute__((ext_vector_type(8)));

union Frag { uint4v u; bf16x8 v; };

static __device__ __forceinline__ unsigned short f2bf_rne(float x) {
  unsigned u = __float_as_uint(x);
  u += 0x7fffu + ((u >> 16) & 1u);
  return (unsigned short)(u >> 16);
}
static __device__ __forceinline__ float bflo(unsigned x) {
  return __uint_as_float(x << 16);
}
static __device__ __forceinline__ float bfhi(unsigned x) {
  return __uint_as_float(x & 0xffff0000u);
}

// ---------- Kernel 1: WG2^T = (E*WG) bf16 [h][f][n], EDH bf16 [h][n] ----------
__global__ __launch_bounds__(128) void prep_kernel(
    const float* __restrict__ G, const float* __restrict__ W,
    const float* __restrict__ bias, const float* __restrict__ a_dst,
    unsigned short* __restrict__ EDH, unsigned short* __restrict__ WG2T) {
  __shared__ float gs[NT * D_IN];  // 8 G rows, 2 KB
  const int tid = threadIdx.x;
  const int n0  = blockIdx.x * NT;
  {
    const float4* src = (const float4*)(G + (size_t)n0 * D_IN);
    float4* dst = (float4*)gs;
    dst[tid] = src[tid];
  }
  __syncthreads();
  const int h = tid >> 5, f = tid & 31;
  float acc[NT];
  const float bb = bias[h * NF + f];
#pragma unroll
  for (int k = 0; k < NT; ++k) acc[k] = bb;
#pragma unroll
  for (int i = 0; i < D_IN; ++i) {
    const float wv = W[(h * D_IN + i) * NF + f];
#pragma unroll
    for (int k = 0; k < NT; ++k) acc[k] = fmaf(gs[k * D_IN + i], wv, acc[k]);
  }
  const float ad = a_dst[h * NF + f];
  float ev[NT];
#pragma unroll
  for (int k = 0; k < NT; ++k) {
    float s = acc[k] * ad;
    s += __shfl_xor(s, 1);  s += __shfl_xor(s, 2);  s += __shfl_xor(s, 4);
    s += __shfl_xor(s, 8);  s += __shfl_xor(s, 16);
    ev[k] = __expf(s);
  }
  union { uint4 u4; unsigned short us[8]; } pk;
#pragma unroll
  for (int k = 0; k < NT; ++k) pk.us[k] = f2bf_rne(acc[k] * ev[k]);
  *(uint4*)&WG2T[(size_t)(h * NF + f) * N_TOK + n0] = pk.u4;
  if (f == 0) {
    union { uint4 u4; unsigned short us[8]; } pe;
#pragma unroll
    for (int k = 0; k < NT; ++k) pe.us[k] = f2bf_rne(ev[k]);
    *(uint4*)&EDH[(size_t)h * N_TOK + n0] = pe.u4;
  }
}

// ---------- Kernel 2: barrier-free masked-softmax-PV ----------
// grid = 256*NS, 512 thr. Block (btile, s): rows b0..b0+15, n-chunk s of N_TOK/NS.
// Wave w: u = w&3 -> n-subslice; v = w>>2 -> heads {2v, 2v+1}, both f-halves.
// Per step (32 n): lane loads its own A-frag elems, exps in-reg, 4 MFMAs.
// NS==1: full rows per block -> direct out (divide+relu in-kernel).
// NS>1 : write partial numerator/denominator to op/dp; comb_kernel finishes.
template <int NS>
__global__ __launch_bounds__(512) void attn_kernel(
    const float* __restrict__ A, const unsigned short* __restrict__ EDH,
    const unsigned short* __restrict__ WG2T, float* __restrict__ op,
    float* __restrict__ dp, float* __restrict__ out) {
  constexpr int NHALF = N_TOK / NS;   // n per block
  constexpr int SLICE = NHALF / 4;    // n per wave
  constexpr int STEPS = SLICE / 32;
  // Overlaid LDS: phase 1 uses Et (NH*NHALF bf16); phase 2 uses accLds+denLds.
  __shared__ __align__(16) char smem[8 * BT * 64 * 4 + 8 * BT * 2 * 4];
  unsigned short* Et = (unsigned short*)smem;
  float* accLds = (float*)smem;                       // 8*BT*64 floats
  float* denLds = (float*)(smem + 8 * BT * 64 * 4);   // 8*BT*2 floats

  const int tid  = threadIdx.x;
  const int lane = tid & 63;
  const int w    = tid >> 6;
  const int u    = w & 3;
  const int v    = w >> 2;
  const int h0   = v * 2;
  const int rowm = lane & 15, g = lane >> 4;
  const int bid  = blockIdx.x;
  const int s    = bid & (NS - 1);
  const int b0   = (bid / NS) * BT;
  const int nbase = s * NHALF + u * SLICE;

  { // E-table slice [h][NHALF] -> LDS
    const uint4* src = (const uint4*)EDH;
    uint4* dst = (uint4*)Et;
    constexpr int tot = NH * NHALF / 8;
#pragma unroll
    for (int i = tid; i < tot; i += 512) {
      const int hh = i / (NHALF / 8), k = i % (NHALF / 8);
      dst[i] = src[hh * (N_TOK / 8) + s * (NHALF / 8) + k];
    }
  }
  __syncthreads();

  const float* aptr = A + (size_t)(b0 + rowm) * N_TOK + nbase + g * 8;
  const unsigned short* bp0 = WG2T + (size_t)((h0    ) * NF +  0 + rowm) * N_TOK + nbase + g * 8;
  const unsigned short* bp1 = WG2T + (size_t)((h0    ) * NF + 16 + rowm) * N_TOK + nbase + g * 8;
  const unsigned short* bp2 = WG2T + (size_t)((h0 + 1) * NF +  0 + rowm) * N_TOK + nbase + g * 8;
  const unsigned short* bp3 = WG2T + (size_t)((h0 + 1) * NF + 16 + rowm) * N_TOK + nbase + g * 8;
  const int eo0 = h0 * NHALF + u * SLICE + g * 8;  // element offset in Et

  f32x4 acc0 = {0.f, 0.f, 0.f, 0.f}, acc1 = {0.f, 0.f, 0.f, 0.f};
  f32x4 acc2 = {0.f, 0.f, 0.f, 0.f}, acc3 = {0.f, 0.f, 0.f, 0.f};
  float dsum0 = 0.f, dsum1 = 0.f;

  float4 a0lo, a0hi, a1lo, a1hi;
  Frag b00, b01, b02, b03, b10, b11, b12, b13;

  // prologue: A for t=0,1; B for t=0
  a0lo = *(const float4*)(aptr);       a0hi = *(const float4*)(aptr + 4);
  a1lo = *(const float4*)(aptr + 32);  a1hi = *(const float4*)(aptr + 36);
  b00.u = *(const uint4v*)(bp0);  b01.u = *(const uint4v*)(bp1);
  b02.u = *(const uint4v*)(bp2);  b03.u = *(const uint4v*)(bp3);

  // No token pasting with digit-leading members (pp-number pitfall): all
  // fragment registers are passed explicitly.
#define BODY(t, ALO, AHI, BC0, BC1, BC2, BC3, BN0, BN1, BN2, BN3) do {         \
    float x0 = __expf(-ALO.x), x1 = __expf(-ALO.y);                            \
    float x2 = __expf(-ALO.z), x3 = __expf(-ALO.w);                            \
    float x4 = __expf(-AHI.x), x5 = __expf(-AHI.y);                            \
    float x6 = __expf(-AHI.z), x7 = __expf(-AHI.w);                            \
    { const int tn = ((t) + 2 < STEPS) ? (t) + 2 : 0;    /* A depth-2 */       \
      ALO = *(const float4*)(aptr + tn * 32);                                  \
      AHI = *(const float4*)(aptr + tn * 32 + 4); }                            \
    { const int tn = ((t) + 1 < STEPS) ? (t) + 1 : 0;    /* B depth-1 */       \
      BN0.u = *(const uint4v*)(bp0 + tn * 32);                                 \
      BN1.u = *(const uint4v*)(bp1 + tn * 32);                                 \
      BN2.u = *(const uint4v*)(bp2 + tn * 32);                                 \
      BN3.u = *(const uint4v*)(bp3 + tn * 32); }                               \
    { const uint4v e0 = *(const uint4v*)&Et[eo0 + (t) * 32];                   \
      const uint4v e1 = *(const uint4v*)&Et[eo0 + NHALF + (t) * 32];           \
      dsum0 = fmaf(x0, bflo(e0[0]), dsum0); dsum0 = fmaf(x1, bfhi(e0[0]), dsum0); \
      dsum0 = fmaf(x2, bflo(e0[1]), dsum0); dsum0 = fmaf(x3, bfhi(e0[1]), dsum0); \
      dsum0 = fmaf(x4, bflo(e0[2]), dsum0); dsum0 = fmaf(x5, bfhi(e0[2]), dsum0); \
      dsum0 = fmaf(x6, bflo(e0[3]), dsum0); dsum0 = fmaf(x7, bfhi(e0[3]), dsum0); \
      dsum1 = fmaf(x0, bflo(e1[0]), dsum1); dsum1 = fmaf(x1, bfhi(e1[0]), dsum1); \
      dsum1 = fmaf(x2, bflo(e1[1]), dsum1); dsum1 = fmaf(x3, bfhi(e1[1]), dsum1); \
      dsum1 = fmaf(x4, bflo(e1[2]), dsum1); dsum1 = fmaf(x5, bfhi(e1[2]), dsum1); \
      dsum1 = fmaf(x6, bflo(e1[3]), dsum1); dsum1 = fmaf(x7, bfhi(e1[3]), dsum1); } \
    Frag af_;                                                                  \
    af_.u[0] = __builtin_amdgcn_perm(__float_as_uint(x1), __float_as_uint(x0), 0x07060302u); \
    af_.u[1] = __builtin_amdgcn_perm(__float_as_uint(x3), __float_as_uint(x2), 0x07060302u); \
    af_.u[2] = __builtin_amdgcn_perm(__float_as_uint(x5), __float_as_uint(x4), 0x07060302u); \
    af_.u[3] = __builtin_amdgcn_perm(__float_as_uint(x7), __float_as_uint(x6), 0x07060302u); \
    acc0 = __builtin_amdgcn_mfma_f32_16x16x32_bf16(af_.v, BC0.v, acc0, 0, 0, 0); \
    acc1 = __builtin_amdgcn_mfma_f32_16x16x32_bf16(af_.v, BC1.v, acc1, 0, 0, 0); \
    acc2 = __builtin_amdgcn_mfma_f32_16x16x32_bf16(af_.v, BC2.v, acc2, 0, 0, 0); \
    acc3 = __builtin_amdgcn_mfma_f32_16x16x32_bf16(af_.v, BC3.v, acc3, 0, 0, 0); \
  } while (0)

#pragma unroll 1
  for (int t = 0; t < STEPS; t += 2) {
    BODY(t,     a0lo, a0hi, b00, b01, b02, b03, b10, b11, b12, b13);
    BODY(t + 1, a1lo, a1hi, b10, b11, b12, b13, b00, b01, b02, b03);
  }
#undef BODY

  // intra-wave denominator reduce over g-groups (lanes l, l^16, l^32, l^48)
  dsum0 += __shfl_xor(dsum0, 16); dsum0 += __shfl_xor(dsum0, 32);
  dsum1 += __shfl_xor(dsum1, 16); dsum1 += __shfl_xor(dsum1, 32);

  // barrier BEFORE reusing the Et region as accLds (LDS overlay)
  __syncthreads();

  if (g == 0) {
    denLds[w * 32 + rowm * 2 + 0] = dsum0;
    denLds[w * 32 + rowm * 2 + 1] = dsum1;
  }
  // partial numerator -> LDS: C/D row=(lane>>4)*4+r, col=lane&15
#pragma unroll
  for (int r = 0; r < 4; ++r) {
    const int row = g * 4 + r;
    float* p = &accLds[w * 1024 + row * 64];
    p[ 0 + rowm] = acc0[r];
    p[16 + rowm] = acc1[r];
    p[32 + rowm] = acc2[r];
    p[48 + rowm] = acc3[r];
  }
  __syncthreads();

  // combine 4 u-slices
  const int row = tid >> 5, cq = tid & 31;
  const int c0 = cq * 4;
  const int h = c0 >> 5, f = c0 & 31;
  const int v2 = h >> 1, dh = h & 1;
  f32x4 num = {0.f, 0.f, 0.f, 0.f};
  float den = 0.f;
#pragma unroll
  for (int uu = 0; uu < 4; ++uu) {
    const int ww = v2 * 4 + uu;
    num += *(const f32x4*)&accLds[ww * 1024 + row * 64 + dh * 32 + f];
    den += denLds[ww * 32 + row * 2 + dh];
  }
  if (NS == 1) {
    const float r = 1.f / den;
    f32x4 res;
    res[0] = fmaxf(num[0] * r, 0.f);
    res[1] = fmaxf(num[1] * r, 0.f);
    res[2] = fmaxf(num[2] * r, 0.f);
    res[3] = fmaxf(num[3] * r, 0.f);
    *(f32x4*)&out[(size_t)(b0 + row) * OUTW + c0] = res;
  } else {
    *(f32x4*)&op[(size_t)s * (N_TOK * OUTW) + (size_t)(b0 + row) * OUTW + c0] = num;
    if ((cq & 7) == 0)
      dp[((size_t)s * N_TOK + b0 + row) * NH + h] = den;
  }
}

// ---------- Kernel 3: combine splits, divide, relu ----------
__global__ __launch_bounds__(256) void comb_kernel(
    const float* __restrict__ op, const float* __restrict__ dp,
    float* __restrict__ out, int NS) {
  const int idx4 = blockIdx.x * 256 + threadIdx.x;  // 131072 float4s
  const int eb = idx4 >> 5;
  const int h  = ((idx4 << 2) & 127) >> 5;
  float4 o; o.x = 0.f; o.y = 0.f; o.z = 0.f; o.w = 0.f;
  float d = 0.f;
  for (int s2 = 0; s2 < NS; ++s2) {
    float4 vv = *(const float4*)(op + (size_t)s2 * (N_TOK * OUTW) + (size_t)idx4 * 4);
    o.x += vv.x; o.y += vv.y; o.z += vv.z; o.w += vv.w;
    d += dp[((size_t)s2 * N_TOK + eb) * NH + h];
  }
  const float r = 1.f / d;
  float4 res;
  res.x = fmaxf(o.x * r, 0.f);
  res.y = fmaxf(o.y * r, 0.f);
  res.z = fmaxf(o.z * r, 0.f);
  res.w = fmaxf(o.w * r, 0.f);
  *(float4*)(out + (size_t)idx4 * 4) = res;
}

extern "C" void kernel_launch(void* const* d_in, const int* in_sizes, int n_in,
                              void* d_out, int out_size, void* d_ws, size_t ws_size,
                              hipStream_t stream) {
  // inputs: 0=X(unused) 1=G 2=A 3=W 4=b 5=a_src(unused) 6=a_dst 7=att_b(unused)
  const float* G     = (const float*)d_in[1];
  const float* A     = (const float*)d_in[2];
  const float* W     = (const float*)d_in[3];
  const float* bias  = (const float*)d_in[4];
  const float* a_dst = (const float*)d_in[6];

  char* ws = (char*)d_ws;
  unsigned short* WG2T = (unsigned short*)ws;               // 1 MB
  unsigned short* EDH  = (unsigned short*)(ws + 1048576);   // 32 KB
  const size_t base = 1048576 + 32768;
  const size_t per_split = (size_t)N_TOK * OUTW * 4 + (size_t)N_TOK * NH * 4;  // 2 MB + 64 KB

  float* op = (float*)(ws + base);
  float* dp = (float*)(ws + base + (size_t)2 * N_TOK * OUTW * 4);
  float* outp = (float*)d_out;

  prep_kernel<<<N_TOK / NT, 128, 0, stream>>>(G, W, bias, a_dst, EDH, WG2T);
  if (ws_size >= base + 2 * per_split) {
    attn_kernel<2><<<256 * 2, 512, 0, stream>>>(A, EDH, WG2T, op, dp, nullptr);
    comb_kernel<<<(N_TOK * OUTW / 4) / 256, 256, 0, stream>>>(op, dp, outp, 2);
  } else {
    attn_kernel<1><<<256, 512, 0, stream>>>(A, EDH, WG2T, nullptr, nullptr, outp);
  }
}

// Round 6
// 40.257 us; speedup vs baseline: 2.0196x; 2.0196x over previous
//
#include <hip/hip_runtime.h>
#include <stdint.h>

#define N_TOK 4096
#define D_IN  64
#define NF    32
#define NH    4
#define OUTW  (NH * NF)        // 128
#define BT    16
#define NT    8
#define CHUNK 128              // n per chunk (4 k-steps of 32)

typedef float        f32x4  __attribute__((ext_vector_type(4)));
typedef unsigned int uint4v __attribute__((ext_vector_type(4)));
typedef __bf16       bf16x8 __attribute__((ext_vector_type(8)));

union Frag { uint4v u; bf16x8 v; };

static __device__ __forceinline__ unsigned short f2bf_rne(float x) {
  unsigned u = __float_as_uint(x);
  u += 0x7fffu + ((u >> 16) & 1u);
  return (unsigned short)(u >> 16);
}

// ---------- Kernel 1: fragment-packed B = [WG2 | ED] ----------
// PB layout: 16-B slot index ((t*9 + set)*64 + g*16 + col), t = n>>5 (k-step),
// g = (n>>3)&3, set<8: (h = set>>1, fhalf = set&1), col = f&15, 8 bf16 (j = n&7).
// set==8: den-frag, col<4 -> ED[n][col], col in 4..15 -> 0.
__global__ __launch_bounds__(128) void prep_kernel(
    const float* __restrict__ G, const float* __restrict__ W,
    const float* __restrict__ bias, const float* __restrict__ a_dst,
    unsigned short* __restrict__ PB) {
  __shared__ float gs[NT * D_IN];  // 8 G rows, 2 KB
  const int tid = threadIdx.x;
  const int n0  = blockIdx.x * NT;
  {
    const float4* src = (const float4*)(G + (size_t)n0 * D_IN);
    float4* dst = (float4*)gs;
    dst[tid] = src[tid];
  }
  __syncthreads();
  const int h = tid >> 5, f = tid & 31;
  float acc[NT];
  const float bb = bias[h * NF + f];
#pragma unroll
  for (int k = 0; k < NT; ++k) acc[k] = bb;
#pragma unroll
  for (int i = 0; i < D_IN; ++i) {
    const float wv = W[(h * D_IN + i) * NF + f];
#pragma unroll
    for (int k = 0; k < NT; ++k) acc[k] = fmaf(gs[k * D_IN + i], wv, acc[k]);
  }
  const float ad = a_dst[h * NF + f];
  float ev[NT];
#pragma unroll
  for (int k = 0; k < NT; ++k) {
    float s = acc[k] * ad;
    s += __shfl_xor(s, 1);  s += __shfl_xor(s, 2);  s += __shfl_xor(s, 4);
    s += __shfl_xor(s, 8);  s += __shfl_xor(s, 16);
    ev[k] = __expf(s);
  }
  const int t   = n0 >> 5;
  const int gq  = (n0 >> 3) & 3;
  const int set = (h << 1) | (f >> 4);
  const int col = f & 15;
  union { uint4 u4; unsigned short us[8]; } pk;
#pragma unroll
  for (int k = 0; k < NT; ++k) pk.us[k] = f2bf_rne(acc[k] * ev[k]);
  *(uint4*)(PB + (size_t)((((t * 9 + set) << 6) + (gq << 4) + col)) * 8) = pk.u4;
  if (f == 0) {  // den-frag cols 0..3
    union { uint4 u4; unsigned short us[8]; } pe;
#pragma unroll
    for (int k = 0; k < NT; ++k) pe.us[k] = f2bf_rne(ev[k]);
    *(uint4*)(PB + (size_t)((((t * 9 + 8) << 6) + (gq << 4) + h)) * 8) = pe.u4;
  }
  if (h == 0 && f >= 4 && f < 16) {  // den-frag cols 4..15 = 0
    uint4 z; z.x = 0u; z.y = 0u; z.z = 0u; z.w = 0u;
    *(uint4*)(PB + (size_t)((((t * 9 + 8) << 6) + (gq << 4) + f)) * 8) = z;
  }
}

// ---------- Kernel 2: fused masked-softmax-PV, pipelined, packed-B ----------
// grid = 256*NS, 512 thr (8 waves). Wave w = set (h = w>>1, fhalf = w&1); every
// wave walks ALL k of its n-range. Per iter: stage A-chunk (reg->exp->bf16->
// swizzled LDS ring), one vmcnt(9) + one barrier, 4 k-steps x 2 MFMA (num+den).
template <int NS>
__global__ __launch_bounds__(512) void attn_kernel(
    const float* __restrict__ A, const unsigned short* __restrict__ PB,
    float* __restrict__ op, float* __restrict__ dp, float* __restrict__ out) {
  constexpr int NHALF = N_TOK / NS;
  constexpr int NIT   = NHALF / CHUNK;
  __shared__ __align__(16) unsigned short ring[3][BT * CHUNK];  // 12 KB
  char* ringb = (char*)&ring[0][0];

  const int tid  = threadIdx.x;
  const int lane = tid & 63;
  const int w    = tid >> 6;
  const int bid  = blockIdx.x;
  const int s    = bid & (NS - 1);
  const int b0   = (bid / NS) * BT;
  const int c0   = 0;
  const int clast = NIT - 1;

  // exp-pass coords: thread = (row srow, 4-col window ncol); wave covers 2 rows
  const int srow = tid >> 5, ncol = tid & 31;
  const float* abase = A + (size_t)(b0 + srow) * N_TOK + s * NHALF + ncol * 4;
  const int wroff = srow * 256 + ((((ncol >> 1) ^ srow) & 15) << 4) + ((ncol & 1) << 3);

  // MFMA frag coords
  const int rowm = lane & 15, g = lane >> 4;
  const char* pbb  = (const char*)PB + (size_t)s * (NHALF / 32) * 9216;
  const char* pown = pbb + (((w << 6) + lane) << 4);
  const char* pden = pbb + (((8 << 6) + lane) << 4);

  f32x4 acc  = {0.f, 0.f, 0.f, 0.f};
  f32x4 accd = {0.f, 0.f, 0.f, 0.f};
  f32x4 a0, a1;
  Frag bo0, bo1, bo2, bo3, bd0, bd1, bd2, bd3;
  Frag co0, co1, co2, co3, cd0, cd1, cd2, cd3;
  int mR = 0, mW = 1;

#define LOADA(dst, cc)                                                         \
  asm volatile("global_load_dwordx4 %0, %1, off"                              \
               : "=v"(dst) : "v"(abase + (size_t)(cc) * CHUNK) : "memory")
#define LOADBO(fr, cc, kk)                                                     \
  asm volatile("global_load_dwordx4 %0, %1, off"                              \
               : "=v"(fr.u)                                                    \
               : "v"(pown + (size_t)((cc) * 4 + (kk)) * 9216) : "memory")
#define LOADBD(fr, cc, kk)                                                     \
  asm volatile("global_load_dwordx4 %0, %1, off"                              \
               : "=v"(fr.u)                                                    \
               : "v"(pden + (size_t)((cc) * 4 + (kk)) * 9216) : "memory")

#define EXPP(AV, mw) do {                                                      \
    float x0 = __expf(-AV[0]), x1 = __expf(-AV[1]);                            \
    float x2 = __expf(-AV[2]), x3 = __expf(-AV[3]);                            \
    uint2 wv_;                                                                 \
    wv_.x = __builtin_amdgcn_perm(__float_as_uint(x1), __float_as_uint(x0), 0x07060302u); \
    wv_.y = __builtin_amdgcn_perm(__float_as_uint(x3), __float_as_uint(x2), 0x07060302u); \
    *(uint2*)(ringb + (mw) * 4096 + wroff) = wv_;                              \
  } while (0)

#define MSTEP(kk, FB, FD) do {                                                 \
    Frag af_;                                                                  \
    af_.v = *(const bf16x8*)(ringb + mR * 4096 + rowm * 256 +                  \
                             ((((kk) * 4 + g) ^ rowm) << 4));                  \
    acc  = __builtin_amdgcn_mfma_f32_16x16x32_bf16(af_.v, FB.v, acc,  0, 0, 0);\
    accd = __builtin_amdgcn_mfma_f32_16x16x32_bf16(af_.v, FD.v, accd, 0, 0, 0);\
  } while (0)

// steady state at entry: outstanding [Bown(c)4, Bden(c)4, A(c+1)] = 9
#define ITER(cc, AV, AV2, CO0, CO1, CO2, CO3, CD0, CD1, CD2, CD3,              \
             NO0, NO1, NO2, NO3, ND0, ND1, ND2, ND3) do {                      \
    { const int cn_ = ((cc) + 1 <= clast) ? (cc) + 1 : clast;                  \
      LOADBO(NO0, cn_, 0); LOADBO(NO1, cn_, 1);                                \
      LOADBO(NO2, cn_, 2); LOADBO(NO3, cn_, 3);                                \
      LOADBD(ND0, cn_, 0); LOADBD(ND1, cn_, 1);                                \
      LOADBD(ND2, cn_, 2); LOADBD(ND3, cn_, 3); }                              \
    { const int ca_ = ((cc) + 2 <= clast) ? (cc) + 2 : clast;                  \
      LOADA(AV2, ca_); }                                                       \
    asm volatile("s_waitcnt vmcnt(9)" ::: "memory");                           \
    __builtin_amdgcn_sched_barrier(0);                                         \
    EXPP(AV, mW);                                                              \
    asm volatile("s_waitcnt lgkmcnt(0)" ::: "memory");                         \
    __builtin_amdgcn_sched_barrier(0);                                         \
    __builtin_amdgcn_s_barrier();                                              \
    MSTEP(0, CO0, CD0); MSTEP(1, CO1, CD1);                                    \
    MSTEP(2, CO2, CD2); MSTEP(3, CO3, CD3);                                    \
    mR = mW; mW = (mW + 1 == 3) ? 0 : mW + 1;                                  \
  } while (0)

  // prologue: outstanding after = [A(c0), B(c0)8, A(c0+1)] = 10
  LOADA(a0, c0);
  LOADBO(bo0, c0, 0); LOADBO(bo1, c0, 1); LOADBO(bo2, c0, 2); LOADBO(bo3, c0, 3);
  LOADBD(bd0, c0, 0); LOADBD(bd1, c0, 1); LOADBD(bd2, c0, 2); LOADBD(bd3, c0, 3);
  LOADA(a1, c0 + 1);
  asm volatile("s_waitcnt vmcnt(9)" ::: "memory");  // a0 landed
  __builtin_amdgcn_sched_barrier(0);
  EXPP(a0, 0);  // chunk c0 -> ring[0]

#pragma unroll 1
  for (int i = 0; i < NIT; i += 2) {
    ITER(c0 + i,     a1, a0, bo0, bo1, bo2, bo3, bd0, bd1, bd2, bd3,
                             co0, co1, co2, co3, cd0, cd1, cd2, cd3);
    ITER(c0 + i + 1, a0, a1, co0, co1, co2, co3, cd0, cd1, cd2, cd3,
                             bo0, bo1, bo2, bo3, bd0, bd1, bd2, bd3);
  }

  // drain all in-flight asm loads before epilogue reuses their dest regs
  asm volatile("s_waitcnt vmcnt(0)" ::: "memory");
  __builtin_amdgcn_sched_barrier(0);

  // C/D layout: row = g*4 + r, col = rowm. Output col = w*16 + rowm.
  // accd col h (0..3) = denominator for head h (identical in every wave).
  if (NS == 1) {
    const int hh = w >> 1;
#pragma unroll
    for (int r = 0; r < 4; ++r) {
      const float den = __shfl(accd[r], g * 16 + hh);
      const float o = acc[r] / den;
      out[(size_t)(b0 + g * 4 + r) * OUTW + w * 16 + rowm] = o > 0.f ? o : 0.f;
    }
  } else {
    float* ob = op + (size_t)s * (N_TOK * OUTW) + (size_t)b0 * OUTW + w * 16 + rowm;
#pragma unroll
    for (int r = 0; r < 4; ++r) ob[(size_t)(g * 4 + r) * OUTW] = acc[r];
    if (w == 0 && rowm < NH) {
#pragma unroll
      for (int r = 0; r < 4; ++r)
        dp[((size_t)s * N_TOK + b0 + g * 4 + r) * NH + rowm] = accd[r];
    }
  }
#undef LOADA
#undef LOADBO
#undef LOADBD
#undef EXPP
#undef MSTEP
#undef ITER
}

// ---------- Kernel 3: combine splits, divide, relu ----------
__global__ __launch_bounds__(256) void comb_kernel(
    const float* __restrict__ op, const float* __restrict__ dp,
    float* __restrict__ out, int NS) {
  const int idx4 = blockIdx.x * 256 + threadIdx.x;  // 131072 float4s
  const int eb = idx4 >> 5;
  const int h  = ((idx4 << 2) & 127) >> 5;
  float4 o; o.x = 0.f; o.y = 0.f; o.z = 0.f; o.w = 0.f;
  float d = 0.f;
  for (int s2 = 0; s2 < NS; ++s2) {
    float4 vv = *(const float4*)(op + (size_t)s2 * (N_TOK * OUTW) + (size_t)idx4 * 4);
    o.x += vv.x; o.y += vv.y; o.z += vv.z; o.w += vv.w;
    d += dp[((size_t)s2 * N_TOK + eb) * NH + h];
  }
  const float r = 1.f / d;
  float4 res;
  res.x = fmaxf(o.x * r, 0.f);
  res.y = fmaxf(o.y * r, 0.f);
  res.z = fmaxf(o.z * r, 0.f);
  res.w = fmaxf(o.w * r, 0.f);
  *(float4*)(out + (size_t)idx4 * 4) = res;
}

extern "C" void kernel_launch(void* const* d_in, const int* in_sizes, int n_in,
                              void* d_out, int out_size, void* d_ws, size_t ws_size,
                              hipStream_t stream) {
  // inputs: 0=X(unused) 1=G 2=A 3=W 4=b 5=a_src(unused) 6=a_dst 7=att_b(unused)
  const float* G     = (const float*)d_in[1];
  const float* A     = (const float*)d_in[2];
  const float* W     = (const float*)d_in[3];
  const float* bias  = (const float*)d_in[4];
  const float* a_dst = (const float*)d_in[6];

  char* ws = (char*)d_ws;
  const size_t PBsz = (size_t)128 * 9 * 1024;  // 1,179,648 B
  const size_t per_split = (size_t)N_TOK * OUTW * 4 + (size_t)N_TOK * NH * 4;

  int NS = 1;
  if (ws_size >= PBsz + 4 * per_split) NS = 4;
  else if (ws_size >= PBsz + 2 * per_split) NS = 2;

  unsigned short* PB = (unsigned short*)ws;
  float* op = (float*)(ws + PBsz);
  float* dp = (float*)(ws + PBsz + (size_t)NS * N_TOK * OUTW * 4);
  float* outp = (float*)d_out;

  prep_kernel<<<N_TOK / NT, 128, 0, stream>>>(G, W, bias, a_dst, PB);
  if (NS == 4) {
    attn_kernel<4><<<256 * 4, 512, 0, stream>>>(A, PB, op, dp, nullptr);
    comb_kernel<<<(N_TOK * OUTW / 4) / 256, 256, 0, stream>>>(op, dp, outp, 4);
  } else if (NS == 2) {
    attn_kernel<2><<<256 * 2, 512, 0, stream>>>(A, PB, op, dp, nullptr);
    comb_kernel<<<(N_TOK * OUTW / 4) / 256, 256, 0, stream>>>(op, dp, outp, 2);
  } else {
    attn_kernel<1><<<256, 512, 0, stream>>>(A, PB, nullptr, nullptr, outp);
  }
}

// Round 8
// 34.043 us; speedup vs baseline: 2.3881x; 1.1825x over previous
//
#include <hip/hip_runtime.h>
#include <stdint.h>

#define N_TOK 4096
#define D_IN  64
#define NF    32
#define NH    4
#define OUTW  (NH * NF)        // 128
#define NT    8
#define CHUNK 128              // n per chunk (4 k-steps of 32)
#define BT    32               // rows per block (RG=2 rowgroups of 16)

typedef float        f32x4  __attribute__((ext_vector_type(4)));
typedef unsigned int uint4v __attribute__((ext_vector_type(4)));
typedef __bf16       bf16x8 __attribute__((ext_vector_type(8)));

union Frag { uint4v u; bf16x8 v; };

static __device__ __forceinline__ unsigned short f2bf_rne(float x) {
  unsigned u = __float_as_uint(x);
  u += 0x7fffu + ((u >> 16) & 1u);
  return (unsigned short)(u >> 16);
}

// ---------- Kernel 1 (verbatim round-6, proven): PB = [WG2 | ED] ----------
// PB 16-B slot ((t*9 + set)*64 + gq*16 + col): t = n>>5, gq = (n>>3)&3,
// set<8: h*2+fhalf, col = f&15; set==8: den-frag (col<4 -> ED[n][col], else 0).
__global__ __launch_bounds__(128) void prep_kernel(
    const float* __restrict__ G, const float* __restrict__ W,
    const float* __restrict__ bias, const float* __restrict__ a_dst,
    unsigned short* __restrict__ PB) {
  __shared__ float gs[NT * D_IN];
  const int tid = threadIdx.x;
  const int n0  = blockIdx.x * NT;
  {
    const float4* src = (const float4*)(G + (size_t)n0 * D_IN);
    float4* dst = (float4*)gs;
    dst[tid] = src[tid];
  }
  __syncthreads();
  const int h = tid >> 5, f = tid & 31;
  float acc[NT];
  const float bb = bias[h * NF + f];
#pragma unroll
  for (int k = 0; k < NT; ++k) acc[k] = bb;
#pragma unroll
  for (int i = 0; i < D_IN; ++i) {
    const float wv = W[(h * D_IN + i) * NF + f];
#pragma unroll
    for (int k = 0; k < NT; ++k) acc[k] = fmaf(gs[k * D_IN + i], wv, acc[k]);
  }
  const float ad = a_dst[h * NF + f];
  float ev[NT];
#pragma unroll
  for (int k = 0; k < NT; ++k) {
    float s = acc[k] * ad;
    s += __shfl_xor(s, 1);  s += __shfl_xor(s, 2);  s += __shfl_xor(s, 4);
    s += __shfl_xor(s, 8);  s += __shfl_xor(s, 16);
    ev[k] = __expf(s);
  }
  const int t   = n0 >> 5;
  const int gq  = (n0 >> 3) & 3;
  const int set = (h << 1) | (f >> 4);
  const int col = f & 31 & 15;
  union { uint4 u4; unsigned short us[8]; } pk;
#pragma unroll
  for (int k = 0; k < NT; ++k) pk.us[k] = f2bf_rne(acc[k] * ev[k]);
  *(uint4*)(PB + (size_t)((((t * 9 + set) << 6) + (gq << 4) + col)) * 8) = pk.u4;
  if (f == 0) {
    union { uint4 u4; unsigned short us[8]; } pe;
#pragma unroll
    for (int k = 0; k < NT; ++k) pe.us[k] = f2bf_rne(ev[k]);
    *(uint4*)(PB + (size_t)((((t * 9 + 8) << 6) + (gq << 4) + h)) * 8) = pe.u4;
  }
  if (h == 0 && f >= 4 && f < 16) {
    uint4 z; z.x = 0u; z.y = 0u; z.z = 0u; z.w = 0u;
    *(uint4*)(PB + (size_t)((((t * 9 + 8) << 6) + (gq << 4) + f)) * 8) = z;
  }
}

// ---------- Kernel 2: round-6 pipeline, single delta = BT 16->32 (RG=2) ----
// grid = (4096/32)*NS, 512 thr (8 waves = sets). Staging: thread=(srow=tid>>4,
// tp=tid&15) loads 8 floats of A row srow, exps, packs, one swizzled 16-B
// ds_write. Per iter: one vmcnt(10) + one barrier, 8 ds_read_b128, 16 MFMA.
template <int NS>
__global__ __launch_bounds__(512) void attn_kernel(
    const float* __restrict__ A, const unsigned short* __restrict__ PB,
    float* __restrict__ op, float* __restrict__ dp, float* __restrict__ out) {
  constexpr int NHALF  = N_TOK / NS;
  constexpr int NIT    = NHALF / CHUNK;
  constexpr int RINGSZ = BT * CHUNK * 2;               // 8192 B
  __shared__ __align__(16) unsigned short ring[3 * BT * CHUNK];  // 24 KB
  char* ringb = (char*)ring;

  const int tid  = threadIdx.x;
  const int lane = tid & 63;
  const int w    = tid >> 6;
  const int bid  = blockIdx.x;
  const int s    = bid & (NS - 1);
  const int b0   = (bid / NS) * BT;

  // staging coords: 512 thr = 32 rows x 16 col-groups of 8
  const int srow = tid >> 4, tp = tid & 15;
  const float* abase = A + (size_t)(b0 + srow) * N_TOK + s * NHALF + tp * 8;
  const int wb0 = srow * 256 + ((tp ^ (srow & 15)) << 4);  // swizzled 16-B slot

  // MFMA frag coords
  const int rowm = lane & 15, g = lane >> 4;
  const char* pbb  = (const char*)PB + (size_t)s * (NHALF / 32) * 9216;
  const char* pown = pbb + (((w << 6) + lane) << 4);
  const char* pden = pbb + (((8 << 6) + lane) << 4);

  f32x4 acc0  = {0.f, 0.f, 0.f, 0.f}, acc1  = {0.f, 0.f, 0.f, 0.f};
  f32x4 accd0 = {0.f, 0.f, 0.f, 0.f}, accd1 = {0.f, 0.f, 0.f, 0.f};
  f32x4 aXa, aXb, aYa, aYb;
  Frag bo0, bo1, bo2, bo3, bd0, bd1, bd2, bd3;
  Frag co0, co1, co2, co3, cd0, cd1, cd2, cd3;
  int mR = 0, mW = 1;

#define LOADA2(d0, d1, cc) do {                                                \
    const float* ap_ = abase + (size_t)(cc) * CHUNK;                           \
    asm volatile("global_load_dwordx4 %0, %1, off"                            \
                 : "=v"(d0) : "v"(ap_) : "memory");                            \
    asm volatile("global_load_dwordx4 %0, %1, off"                            \
                 : "=v"(d1) : "v"(ap_ + 4) : "memory");                        \
  } while (0)
#define LOADBO(fr, cc, kk)                                                     \
  asm volatile("global_load_dwordx4 %0, %1, off"                              \
               : "=v"(fr.u)                                                    \
               : "v"(pown + (size_t)((cc) * 4 + (kk)) * 9216) : "memory")
#define LOADBD(fr, cc, kk)                                                     \
  asm volatile("global_load_dwordx4 %0, %1, off"                              \
               : "=v"(fr.u)                                                    \
               : "v"(pden + (size_t)((cc) * 4 + (kk)) * 9216) : "memory")

#define EXPP(AV0, AV1, mw) do {                                                \
    float x0 = __expf(-AV0[0]), x1 = __expf(-AV0[1]);                          \
    float x2 = __expf(-AV0[2]), x3 = __expf(-AV0[3]);                          \
    float x4 = __expf(-AV1[0]), x5 = __expf(-AV1[1]);                          \
    float x6 = __expf(-AV1[2]), x7 = __expf(-AV1[3]);                          \
    uint4v t_;                                                                 \
    t_[0] = __builtin_amdgcn_perm(__float_as_uint(x1), __float_as_uint(x0), 0x07060302u); \
    t_[1] = __builtin_amdgcn_perm(__float_as_uint(x3), __float_as_uint(x2), 0x07060302u); \
    t_[2] = __builtin_amdgcn_perm(__float_as_uint(x5), __float_as_uint(x4), 0x07060302u); \
    t_[3] = __builtin_amdgcn_perm(__float_as_uint(x7), __float_as_uint(x6), 0x07060302u); \
    *(uint4v*)(ringb + (mw) * RINGSZ + wb0) = t_;                              \
  } while (0)

#define MSTEP(rg, kk, FB, FD) do {                                             \
    Frag af_;                                                                  \
    af_.v = *(const bf16x8*)(ringb + mR * RINGSZ + ((rg) * 16 + rowm) * 256 +  \
                             ((((kk) * 4 + g) ^ rowm) << 4));                  \
    if ((rg) == 0) {                                                           \
      acc0  = __builtin_amdgcn_mfma_f32_16x16x32_bf16(af_.v, FB.v, acc0,  0, 0, 0); \
      accd0 = __builtin_amdgcn_mfma_f32_16x16x32_bf16(af_.v, FD.v, accd0, 0, 0, 0); \
    } else {                                                                   \
      acc1  = __builtin_amdgcn_mfma_f32_16x16x32_bf16(af_.v, FB.v, acc1,  0, 0, 0); \
      accd1 = __builtin_amdgcn_mfma_f32_16x16x32_bf16(af_.v, FD.v, accd1, 0, 0, 0); \
    }                                                                          \
  } while (0)

// steady entry queue: [B(c)x8, A(c+1)x2] = 10; issue 10 more; vmcnt(10)
// drains B(c)+A(c+1), keeps B(c+1)+A(c+2) in flight.
#define ITER(cc, AC0, AC1, AN0, AN1, CO0, CO1, CO2, CO3, CD0, CD1, CD2, CD3,   \
             NO0, NO1, NO2, NO3, ND0, ND1, ND2, ND3) do {                      \
    { const int cb_ = ((cc) + 1 < NIT) ? (cc) + 1 : NIT - 1;                   \
      LOADBO(NO0, cb_, 0); LOADBO(NO1, cb_, 1);                                \
      LOADBO(NO2, cb_, 2); LOADBO(NO3, cb_, 3);                                \
      LOADBD(ND0, cb_, 0); LOADBD(ND1, cb_, 1);                                \
      LOADBD(ND2, cb_, 2); LOADBD(ND3, cb_, 3); }                              \
    { const int ca_ = ((cc) + 2 < NIT) ? (cc) + 2 : NIT - 1;                   \
      LOADA2(AN0, AN1, ca_); }                                                 \
    asm volatile("s_waitcnt vmcnt(10)" ::: "memory");                          \
    __builtin_amdgcn_sched_barrier(0);                                         \
    EXPP(AC0, AC1, mW);                                                        \
    asm volatile("s_waitcnt lgkmcnt(0)" ::: "memory");                         \
    __builtin_amdgcn_sched_barrier(0);                                         \
    __builtin_amdgcn_s_barrier();                                              \
    MSTEP(0, 0, CO0, CD0); MSTEP(1, 0, CO0, CD0);                              \
    MSTEP(0, 1, CO1, CD1); MSTEP(1, 1, CO1, CD1);                              \
    MSTEP(0, 2, CO2, CD2); MSTEP(1, 2, CO2, CD2);                              \
    MSTEP(0, 3, CO3, CD3); MSTEP(1, 3, CO3, CD3);                              \
    mR = mW; mW = (mW + 1 == 3) ? 0 : mW + 1;                                  \
  } while (0)

  // prologue: queue [A(0)x2, B(0)x8, A(1)x2] = 12; vmcnt(10) drains A(0)
  LOADA2(aXa, aXb, 0);
  LOADBO(bo0, 0, 0); LOADBO(bo1, 0, 1); LOADBO(bo2, 0, 2); LOADBO(bo3, 0, 3);
  LOADBD(bd0, 0, 0); LOADBD(bd1, 0, 1); LOADBD(bd2, 0, 2); LOADBD(bd3, 0, 3);
  LOADA2(aYa, aYb, 1);
  asm volatile("s_waitcnt vmcnt(10)" ::: "memory");
  __builtin_amdgcn_sched_barrier(0);
  EXPP(aXa, aXb, 0);

#pragma unroll 1
  for (int i = 0; i < NIT; i += 2) {
    ITER(i,     aYa, aYb, aXa, aXb, bo0, bo1, bo2, bo3, bd0, bd1, bd2, bd3,
                                    co0, co1, co2, co3, cd0, cd1, cd2, cd3);
    ITER(i + 1, aXa, aXb, aYa, aYb, co0, co1, co2, co3, cd0, cd1, cd2, cd3,
                                    bo0, bo1, bo2, bo3, bd0, bd1, bd2, bd3);
  }

  // drain in-flight asm loads before epilogue reuses their dest regs
  asm volatile("s_waitcnt vmcnt(0)" ::: "memory");
  __builtin_amdgcn_sched_barrier(0);

  // C/D: row = rg*16 + g*4 + r, col = rowm. Wave w covers output cols w*16+.
  // accd col h (0..3) = denominator for head h (identical across waves).
  if (NS == 1) {
    const int hh = w >> 1;
#pragma unroll
    for (int r = 0; r < 4; ++r) {
      const float dn0 = __shfl(accd0[r], g * 16 + hh);
      const float o0 = acc0[r] / dn0;
      out[(size_t)(b0 + g * 4 + r) * OUTW + w * 16 + rowm] = o0 > 0.f ? o0 : 0.f;
      const float dn1 = __shfl(accd1[r], g * 16 + hh);
      const float o1 = acc1[r] / dn1;
      out[(size_t)(b0 + 16 + g * 4 + r) * OUTW + w * 16 + rowm] = o1 > 0.f ? o1 : 0.f;
    }
  } else {
    float* ob = op + (size_t)s * (N_TOK * OUTW) + (size_t)b0 * OUTW + w * 16 + rowm;
#pragma unroll
    for (int r = 0; r < 4; ++r) {
      ob[(size_t)(g * 4 + r) * OUTW]      = acc0[r];
      ob[(size_t)(16 + g * 4 + r) * OUTW] = acc1[r];
    }
    if (w == 0 && rowm < NH) {
#pragma unroll
      for (int r = 0; r < 4; ++r) {
        dp[((size_t)s * N_TOK + b0 + g * 4 + r) * NH + rowm]      = accd0[r];
        dp[((size_t)s * N_TOK + b0 + 16 + g * 4 + r) * NH + rowm] = accd1[r];
      }
    }
  }
#undef LOADA2
#undef LOADBO
#undef LOADBD
#undef EXPP
#undef MSTEP
#undef ITER
}

// ---------- Kernel 3: combine splits, divide, relu ----------
__global__ __launch_bounds__(256) void comb_kernel(
    const float* __restrict__ op, const float* __restrict__ dp,
    float* __restrict__ out, int NS) {
  const int idx4 = blockIdx.x * 256 + threadIdx.x;
  const int eb = idx4 >> 5;
  const int h  = ((idx4 << 2) & 127) >> 5;
  float4 o; o.x = 0.f; o.y = 0.f; o.z = 0.f; o.w = 0.f;
  float d = 0.f;
  for (int s2 = 0; s2 < NS; ++s2) {
    float4 vv = *(const float4*)(op + (size_t)s2 * (N_TOK * OUTW) + (size_t)idx4 * 4);
    o.x += vv.x; o.y += vv.y; o.z += vv.z; o.w += vv.w;
    d += dp[((size_t)s2 * N_TOK + eb) * NH + h];
  }
  const float r = 1.f / d;
  float4 res;
  res.x = fmaxf(o.x * r, 0.f);
  res.y = fmaxf(o.y * r, 0.f);
  res.z = fmaxf(o.z * r, 0.f);
  res.w = fmaxf(o.w * r, 0.f);
  *(float4*)(out + (size_t)idx4 * 4) = res;
}

extern "C" void kernel_launch(void* const* d_in, const int* in_sizes, int n_in,
                              void* d_out, int out_size, void* d_ws, size_t ws_size,
                              hipStream_t stream) {
  // inputs: 0=X(unused) 1=G 2=A 3=W 4=b 5=a_src(unused) 6=a_dst 7=att_b(unused)
  const float* G     = (const float*)d_in[1];
  const float* A     = (const float*)d_in[2];
  const float* W     = (const float*)d_in[3];
  const float* bias  = (const float*)d_in[4];
  const float* a_dst = (const float*)d_in[6];

  char* ws = (char*)d_ws;
  const size_t PBsz = (size_t)128 * 9 * 1024;  // 1,179,648 B
  const size_t per_split = (size_t)N_TOK * OUTW * 4 + (size_t)N_TOK * NH * 4;

  unsigned short* PB = (unsigned short*)ws;
  float* op = (float*)(ws + PBsz);
  float* outp = (float*)d_out;

  prep_kernel<<<N_TOK / NT, 128, 0, stream>>>(G, W, bias, a_dst, PB);
  if (ws_size >= PBsz + 4 * per_split) {
    float* dp = (float*)(ws + PBsz + 4 * (size_t)N_TOK * OUTW * 4);
    attn_kernel<4><<<(N_TOK / BT) * 4, 512, 0, stream>>>(A, PB, op, dp, nullptr);
    comb_kernel<<<(N_TOK * OUTW / 4) / 256, 256, 0, stream>>>(op, dp, outp, 4);
  } else if (ws_size >= PBsz + 2 * per_split) {
    float* dp = (float*)(ws + PBsz + 2 * (size_t)N_TOK * OUTW * 4);
    attn_kernel<2><<<(N_TOK / BT) * 2, 512, 0, stream>>>(A, PB, op, dp, nullptr);
    comb_kernel<<<(N_TOK * OUTW / 4) / 256, 256, 0, stream>>>(op, dp, outp, 2);
  } else {
    attn_kernel<1><<<N_TOK / BT, 512, 0, stream>>>(A, PB, nullptr, nullptr, outp);
  }
}

// Round 9
// 30.827 us; speedup vs baseline: 2.6374x; 1.1044x over previous
//
#include <hip/hip_runtime.h>
#include <stdint.h>

#define N_TOK 4096
#define D_IN  64
#define NF    32
#define NH    4
#define OUTW  (NH * NF)        // 128
#define NT    8
#define CHUNK 128              // n per chunk (4 k-steps of 32)
#define BT    32               // rows per block (2 rowgroups of 16)

typedef float        f32x4  __attribute__((ext_vector_type(4)));
typedef unsigned int uint4v __attribute__((ext_vector_type(4)));
typedef __bf16       bf16x8 __attribute__((ext_vector_type(8)));

union Frag { uint4v u; bf16x8 v; };

static __device__ __forceinline__ unsigned short f2bf_rne(float x) {
  unsigned u = __float_as_uint(x);
  u += 0x7fffu + ((u >> 16) & 1u);
  return (unsigned short)(u >> 16);
}

// ---------- Kernel 1 (proven): PB = [WG2 | ED] fragment-packed ----------
// PB 16-B slot ((t*9 + set)*64 + gq*16 + col): t = n>>5, gq = (n>>3)&3,
// set<8: h*2+fhalf, col = f&15; set==8: den-frag (col<4 -> ED[n][col], else 0).
__global__ __launch_bounds__(128) void prep_kernel(
    const float* __restrict__ G, const float* __restrict__ W,
    const float* __restrict__ bias, const float* __restrict__ a_dst,
    unsigned short* __restrict__ PB) {
  __shared__ float gs[NT * D_IN];
  const int tid = threadIdx.x;
  const int n0  = blockIdx.x * NT;
  {
    const float4* src = (const float4*)(G + (size_t)n0 * D_IN);
    float4* dst = (float4*)gs;
    dst[tid] = src[tid];
  }
  __syncthreads();
  const int h = tid >> 5, f = tid & 31;
  float acc[NT];
  const float bb = bias[h * NF + f];
#pragma unroll
  for (int k = 0; k < NT; ++k) acc[k] = bb;
#pragma unroll
  for (int i = 0; i < D_IN; ++i) {
    const float wv = W[(h * D_IN + i) * NF + f];
#pragma unroll
    for (int k = 0; k < NT; ++k) acc[k] = fmaf(gs[k * D_IN + i], wv, acc[k]);
  }
  const float ad = a_dst[h * NF + f];
  float ev[NT];
#pragma unroll
  for (int k = 0; k < NT; ++k) {
    float s = acc[k] * ad;
    s += __shfl_xor(s, 1);  s += __shfl_xor(s, 2);  s += __shfl_xor(s, 4);
    s += __shfl_xor(s, 8);  s += __shfl_xor(s, 16);
    ev[k] = __expf(s);
  }
  const int t   = n0 >> 5;
  const int gq  = (n0 >> 3) & 3;
  const int set = (h << 1) | (f >> 4);
  const int col = f & 15;
  union { uint4 u4; unsigned short us[8]; } pk;
#pragma unroll
  for (int k = 0; k < NT; ++k) pk.us[k] = f2bf_rne(acc[k] * ev[k]);
  *(uint4*)(PB + (size_t)((((t * 9 + set) << 6) + (gq << 4) + col)) * 8) = pk.u4;
  if (f == 0) {
    union { uint4 u4; unsigned short us[8]; } pe;
#pragma unroll
    for (int k = 0; k < NT; ++k) pe.us[k] = f2bf_rne(ev[k]);
    *(uint4*)(PB + (size_t)((((t * 9 + 8) << 6) + (gq << 4) + h)) * 8) = pe.u4;
  }
  if (h == 0 && f >= 4 && f < 16) {
    uint4 z; z.x = 0u; z.y = 0u; z.z = 0u; z.w = 0u;
    *(uint4*)(PB + (size_t)((((t * 9 + 8) << 6) + (gq << 4) + f)) * 8) = z;
  }
}

// ---------- Kernel 2: round-8 pipeline, single delta = wave-0-only den ------
// grid = (4096/32)*NS, 512 thr (8 waves = sets). Wave 0 additionally computes
// the denominator (identical across waves in round 8 -> 7/8 of den B traffic
// and den MFMAs were redundant). w0 queue: vmcnt(10); w>0 queue: vmcnt(6).
template <int NS>
__global__ __launch_bounds__(512) void attn_kernel(
    const float* __restrict__ A, const unsigned short* __restrict__ PB,
    float* __restrict__ op, float* __restrict__ dp, float* __restrict__ out) {
  constexpr int NHALF  = N_TOK / NS;
  constexpr int NIT    = NHALF / CHUNK;
  constexpr int RINGSZ = BT * CHUNK * 2;               // 8192 B
  __shared__ __align__(16) unsigned short ring[3 * BT * CHUNK];  // 24 KB
  __shared__ float denLds[BT * NH];                    // 512 B
  char* ringb = (char*)ring;

  const int tid  = threadIdx.x;
  const int lane = tid & 63;
  const int w    = tid >> 6;
  const int bid  = blockIdx.x;
  const int s    = bid & (NS - 1);
  const int b0   = (bid / NS) * BT;

  // staging coords: 512 thr = 32 rows x 16 col-groups of 8
  const int srow = tid >> 4, tp = tid & 15;
  const float* abase = A + (size_t)(b0 + srow) * N_TOK + s * NHALF + tp * 8;
  const int wb0 = srow * 256 + ((tp ^ (srow & 15)) << 4);  // swizzled 16-B slot

  // MFMA frag coords
  const int rowm = lane & 15, g = lane >> 4;
  const char* pbb  = (const char*)PB + (size_t)s * (NHALF / 32) * 9216;
  const char* pown = pbb + (((w << 6) + lane) << 4);
  const char* pden = pbb + (((8 << 6) + lane) << 4);

  f32x4 acc0  = {0.f, 0.f, 0.f, 0.f}, acc1  = {0.f, 0.f, 0.f, 0.f};
  f32x4 accd0 = {0.f, 0.f, 0.f, 0.f}, accd1 = {0.f, 0.f, 0.f, 0.f};
  f32x4 aXa, aXb, aYa, aYb;
  Frag bo0, bo1, bo2, bo3, bd0, bd1, bd2, bd3;
  Frag co0, co1, co2, co3, cd0, cd1, cd2, cd3;
  int mR = 0, mW = 1;

#define LOADA2(d0, d1, cc) do {                                                \
    const float* ap_ = abase + (size_t)(cc) * CHUNK;                           \
    asm volatile("global_load_dwordx4 %0, %1, off"                            \
                 : "=v"(d0) : "v"(ap_) : "memory");                            \
    asm volatile("global_load_dwordx4 %0, %1, off"                            \
                 : "=v"(d1) : "v"(ap_ + 4) : "memory");                        \
  } while (0)
#define LOADBO(fr, cc, kk)                                                     \
  asm volatile("global_load_dwordx4 %0, %1, off"                              \
               : "=v"(fr.u)                                                    \
               : "v"(pown + (size_t)((cc) * 4 + (kk)) * 9216) : "memory")
#define LOADBD(fr, cc, kk)                                                     \
  asm volatile("global_load_dwordx4 %0, %1, off"                              \
               : "=v"(fr.u)                                                    \
               : "v"(pden + (size_t)((cc) * 4 + (kk)) * 9216) : "memory")

#define EXPP(AV0, AV1, mw) do {                                                \
    float x0 = __expf(-AV0[0]), x1 = __expf(-AV0[1]);                          \
    float x2 = __expf(-AV0[2]), x3 = __expf(-AV0[3]);                          \
    float x4 = __expf(-AV1[0]), x5 = __expf(-AV1[1]);                          \
    float x6 = __expf(-AV1[2]), x7 = __expf(-AV1[3]);                          \
    uint4v t_;                                                                 \
    t_[0] = __builtin_amdgcn_perm(__float_as_uint(x1), __float_as_uint(x0), 0x07060302u); \
    t_[1] = __builtin_amdgcn_perm(__float_as_uint(x3), __float_as_uint(x2), 0x07060302u); \
    t_[2] = __builtin_amdgcn_perm(__float_as_uint(x5), __float_as_uint(x4), 0x07060302u); \
    t_[3] = __builtin_amdgcn_perm(__float_as_uint(x7), __float_as_uint(x6), 0x07060302u); \
    *(uint4v*)(ringb + (mw) * RINGSZ + wb0) = t_;                              \
  } while (0)

// own+den MFMA pair (wave 0)
#define MSTEPD(rg, kk, FB, FD) do {                                            \
    Frag af_;                                                                  \
    af_.v = *(const bf16x8*)(ringb + mR * RINGSZ + ((rg) * 16 + rowm) * 256 +  \
                             ((((kk) * 4 + g) ^ rowm) << 4));                  \
    if ((rg) == 0) {                                                           \
      acc0  = __builtin_amdgcn_mfma_f32_16x16x32_bf16(af_.v, FB.v, acc0,  0, 0, 0); \
      accd0 = __builtin_amdgcn_mfma_f32_16x16x32_bf16(af_.v, FD.v, accd0, 0, 0, 0); \
    } else {                                                                   \
      acc1  = __builtin_amdgcn_mfma_f32_16x16x32_bf16(af_.v, FB.v, acc1,  0, 0, 0); \
      accd1 = __builtin_amdgcn_mfma_f32_16x16x32_bf16(af_.v, FD.v, accd1, 0, 0, 0); \
    }                                                                          \
  } while (0)
// own-only MFMA (waves 1..7)
#define MSTEPO(rg, kk, FB) do {                                                \
    Frag af_;                                                                  \
    af_.v = *(const bf16x8*)(ringb + mR * RINGSZ + ((rg) * 16 + rowm) * 256 +  \
                             ((((kk) * 4 + g) ^ rowm) << 4));                  \
    if ((rg) == 0)                                                             \
      acc0 = __builtin_amdgcn_mfma_f32_16x16x32_bf16(af_.v, FB.v, acc0, 0, 0, 0); \
    else                                                                       \
      acc1 = __builtin_amdgcn_mfma_f32_16x16x32_bf16(af_.v, FB.v, acc1, 0, 0, 0); \
  } while (0)

// wave 0: steady entry [B(c)x8, A(c+1)x2] = 10; issue 10; vmcnt(10)
#define ITERD(cc, AC0, AC1, AN0, AN1, CO0, CO1, CO2, CO3, CD0, CD1, CD2, CD3,  \
              NO0, NO1, NO2, NO3, ND0, ND1, ND2, ND3) do {                     \
    { const int cb_ = ((cc) + 1 < NIT) ? (cc) + 1 : NIT - 1;                   \
      LOADBO(NO0, cb_, 0); LOADBO(NO1, cb_, 1);                                \
      LOADBO(NO2, cb_, 2); LOADBO(NO3, cb_, 3);                                \
      LOADBD(ND0, cb_, 0); LOADBD(ND1, cb_, 1);                                \
      LOADBD(ND2, cb_, 2); LOADBD(ND3, cb_, 3); }                              \
    { const int ca_ = ((cc) + 2 < NIT) ? (cc) + 2 : NIT - 1;                   \
      LOADA2(AN0, AN1, ca_); }                                                 \
    asm volatile("s_waitcnt vmcnt(10)" ::: "memory");                          \
    __builtin_amdgcn_sched_barrier(0);                                         \
    EXPP(AC0, AC1, mW);                                                        \
    asm volatile("s_waitcnt lgkmcnt(0)" ::: "memory");                         \
    __builtin_amdgcn_sched_barrier(0);                                         \
    __builtin_amdgcn_s_barrier();                                              \
    MSTEPD(0, 0, CO0, CD0); MSTEPD(1, 0, CO0, CD0);                            \
    MSTEPD(0, 1, CO1, CD1); MSTEPD(1, 1, CO1, CD1);                            \
    MSTEPD(0, 2, CO2, CD2); MSTEPD(1, 2, CO2, CD2);                            \
    MSTEPD(0, 3, CO3, CD3); MSTEPD(1, 3, CO3, CD3);                            \
    mR = mW; mW = (mW + 1 == 3) ? 0 : mW + 1;                                  \
  } while (0)
// waves 1..7: steady entry [B(c)x4, A(c+1)x2] = 6; issue 6; vmcnt(6)
#define ITERO(cc, AC0, AC1, AN0, AN1, CO0, CO1, CO2, CO3,                      \
              NO0, NO1, NO2, NO3) do {                                         \
    { const int cb_ = ((cc) + 1 < NIT) ? (cc) + 1 : NIT - 1;                   \
      LOADBO(NO0, cb_, 0); LOADBO(NO1, cb_, 1);                                \
      LOADBO(NO2, cb_, 2); LOADBO(NO3, cb_, 3); }                              \
    { const int ca_ = ((cc) + 2 < NIT) ? (cc) + 2 : NIT - 1;                   \
      LOADA2(AN0, AN1, ca_); }                                                 \
    asm volatile("s_waitcnt vmcnt(6)" ::: "memory");                           \
    __builtin_amdgcn_sched_barrier(0);                                         \
    EXPP(AC0, AC1, mW);                                                        \
    asm volatile("s_waitcnt lgkmcnt(0)" ::: "memory");                         \
    __builtin_amdgcn_sched_barrier(0);                                         \
    __builtin_amdgcn_s_barrier();                                              \
    MSTEPO(0, 0, CO0); MSTEPO(1, 0, CO0);                                      \
    MSTEPO(0, 1, CO1); MSTEPO(1, 1, CO1);                                      \
    MSTEPO(0, 2, CO2); MSTEPO(1, 2, CO2);                                      \
    MSTEPO(0, 3, CO3); MSTEPO(1, 3, CO3);                                      \
    mR = mW; mW = (mW + 1 == 3) ? 0 : mW + 1;                                  \
  } while (0)

  if (w == 0) {
    // prologue: [A(0)x2, B(0)x8, A(1)x2] = 12; vmcnt(10) drains A(0)
    LOADA2(aXa, aXb, 0);
    LOADBO(bo0, 0, 0); LOADBO(bo1, 0, 1); LOADBO(bo2, 0, 2); LOADBO(bo3, 0, 3);
    LOADBD(bd0, 0, 0); LOADBD(bd1, 0, 1); LOADBD(bd2, 0, 2); LOADBD(bd3, 0, 3);
    LOADA2(aYa, aYb, 1);
    asm volatile("s_waitcnt vmcnt(10)" ::: "memory");
    __builtin_amdgcn_sched_barrier(0);
    EXPP(aXa, aXb, 0);
#pragma unroll 1
    for (int i = 0; i < NIT; i += 2) {
      ITERD(i,     aYa, aYb, aXa, aXb, bo0, bo1, bo2, bo3, bd0, bd1, bd2, bd3,
                                       co0, co1, co2, co3, cd0, cd1, cd2, cd3);
      ITERD(i + 1, aXa, aXb, aYa, aYb, co0, co1, co2, co3, cd0, cd1, cd2, cd3,
                                       bo0, bo1, bo2, bo3, bd0, bd1, bd2, bd3);
    }
  } else {
    // prologue: [A(0)x2, B(0)x4, A(1)x2] = 8; vmcnt(6) drains A(0)
    LOADA2(aXa, aXb, 0);
    LOADBO(bo0, 0, 0); LOADBO(bo1, 0, 1); LOADBO(bo2, 0, 2); LOADBO(bo3, 0, 3);
    LOADA2(aYa, aYb, 1);
    asm volatile("s_waitcnt vmcnt(6)" ::: "memory");
    __builtin_amdgcn_sched_barrier(0);
    EXPP(aXa, aXb, 0);
#pragma unroll 1
    for (int i = 0; i < NIT; i += 2) {
      ITERO(i,     aYa, aYb, aXa, aXb, bo0, bo1, bo2, bo3,
                                       co0, co1, co2, co3);
      ITERO(i + 1, aXa, aXb, aYa, aYb, co0, co1, co2, co3,
                                       bo0, bo1, bo2, bo3);
    }
  }

  // drain in-flight asm loads before epilogue reuses their dest regs
  asm volatile("s_waitcnt vmcnt(0)" ::: "memory");
  __builtin_amdgcn_sched_barrier(0);

  // C/D: row = rg*16 + g*4 + r, col = rowm. Wave w covers output cols w*16+.
  // accd (wave 0) col h = denominator for head h.
  if (NS == 1) {
    if (w == 0 && rowm < NH) {
#pragma unroll
      for (int r = 0; r < 4; ++r) {
        denLds[(g * 4 + r) * NH + rowm]      = accd0[r];
        denLds[(16 + g * 4 + r) * NH + rowm] = accd1[r];
      }
    }
    __syncthreads();
    const int hh = w >> 1;
#pragma unroll
    for (int r = 0; r < 4; ++r) {
      const float o0 = acc0[r] / denLds[(g * 4 + r) * NH + hh];
      out[(size_t)(b0 + g * 4 + r) * OUTW + w * 16 + rowm] = o0 > 0.f ? o0 : 0.f;
      const float o1 = acc1[r] / denLds[(16 + g * 4 + r) * NH + hh];
      out[(size_t)(b0 + 16 + g * 4 + r) * OUTW + w * 16 + rowm] = o1 > 0.f ? o1 : 0.f;
    }
  } else {
    float* ob = op + (size_t)s * (N_TOK * OUTW) + (size_t)b0 * OUTW + w * 16 + rowm;
#pragma unroll
    for (int r = 0; r < 4; ++r) {
      ob[(size_t)(g * 4 + r) * OUTW]      = acc0[r];
      ob[(size_t)(16 + g * 4 + r) * OUTW] = acc1[r];
    }
    if (w == 0 && rowm < NH) {
#pragma unroll
      for (int r = 0; r < 4; ++r) {
        dp[((size_t)s * N_TOK + b0 + g * 4 + r) * NH + rowm]      = accd0[r];
        dp[((size_t)s * N_TOK + b0 + 16 + g * 4 + r) * NH + rowm] = accd1[r];
      }
    }
  }
#undef LOADA2
#undef LOADBO
#undef LOADBD
#undef EXPP
#undef MSTEPD
#undef MSTEPO
#undef ITERD
#undef ITERO
}

// ---------- Kernel 3: combine splits, divide, relu ----------
__global__ __launch_bounds__(256) void comb_kernel(
    const float* __restrict__ op, const float* __restrict__ dp,
    float* __restrict__ out, int NS) {
  const int idx4 = blockIdx.x * 256 + threadIdx.x;
  const int eb = idx4 >> 5;
  const int h  = ((idx4 << 2) & 127) >> 5;
  float4 o; o.x = 0.f; o.y = 0.f; o.z = 0.f; o.w = 0.f;
  float d = 0.f;
  for (int s2 = 0; s2 < NS; ++s2) {
    float4 vv = *(const float4*)(op + (size_t)s2 * (N_TOK * OUTW) + (size_t)idx4 * 4);
    o.x += vv.x; o.y += vv.y; o.z += vv.z; o.w += vv.w;
    d += dp[((size_t)s2 * N_TOK + eb) * NH + h];
  }
  const float r = 1.f / d;
  float4 res;
  res.x = fmaxf(o.x * r, 0.f);
  res.y = fmaxf(o.y * r, 0.f);
  res.z = fmaxf(o.z * r, 0.f);
  res.w = fmaxf(o.w * r, 0.f);
  *(float4*)(out + (size_t)idx4 * 4) = res;
}

extern "C" void kernel_launch(void* const* d_in, const int* in_sizes, int n_in,
                              void* d_out, int out_size, void* d_ws, size_t ws_size,
                              hipStream_t stream) {
  // inputs: 0=X(unused) 1=G 2=A 3=W 4=b 5=a_src(unused) 6=a_dst 7=att_b(unused)
  const float* G     = (const float*)d_in[1];
  const float* A     = (const float*)d_in[2];
  const float* W     = (const float*)d_in[3];
  const float* bias  = (const float*)d_in[4];
  const float* a_dst = (const float*)d_in[6];

  char* ws = (char*)d_ws;
  const size_t PBsz = (size_t)128 * 9 * 1024;  // 1,179,648 B
  const size_t per_split = (size_t)N_TOK * OUTW * 4 + (size_t)N_TOK * NH * 4;

  unsigned short* PB = (unsigned short*)ws;
  float* op = (float*)(ws + PBsz);
  float* outp = (float*)d_out;

  prep_kernel<<<N_TOK / NT, 128, 0, stream>>>(G, W, bias, a_dst, PB);
  if (ws_size >= PBsz + 4 * per_split) {
    float* dp = (float*)(ws + PBsz + 4 * (size_t)N_TOK * OUTW * 4);
    attn_kernel<4><<<(N_TOK / BT) * 4, 512, 0, stream>>>(A, PB, op, dp, nullptr);
    comb_kernel<<<(N_TOK * OUTW / 4) / 256, 256, 0, stream>>>(op, dp, outp, 4);
  } else if (ws_size >= PBsz + 2 * per_split) {
    float* dp = (float*)(ws + PBsz + 2 * (size_t)N_TOK * OUTW * 4);
    attn_kernel<2><<<(N_TOK / BT) * 2, 512, 0, stream>>>(A, PB, op, dp, nullptr);
    comb_kernel<<<(N_TOK * OUTW / 4) / 256, 256, 0, stream>>>(op, dp, outp, 2);
  } else {
    attn_kernel<1><<<N_TOK / BT, 512, 0, stream>>>(A, PB, nullptr, nullptr, outp);
  }
}